// Round 9
// baseline (95.371 us; speedup 1.0000x reference)
//
#include <hip/hip_runtime.h>
#include <cfloat>

#define Bn 1024
#define Ln 200
#define En 128
#define An 128
#define Hn 4

// ---- ws layout (total 1974272 B; proven ws_size >= 2363392) ----
#define WS_POSW1   0                        // 208*128*4 = 106496 (rows 200..207 zero)
#define WS_W1FRAG  106496                   // 2048 entries * 16B = 32768
#define WS_ATTPOOL 139264                   // 1024 slots * SLOT (pooled bf16[512] per b)
#define SLOT       1664
#define WS_WOUTT   1843200                  // 128*512 bf16 = 131072
#define WS_NEEDED  1974272

using f32x4  = __attribute__((ext_vector_type(4))) float;
using bf16x8 = __attribute__((ext_vector_type(8))) short;

__device__ __forceinline__ unsigned short f2bf(float f){
    unsigned u = __builtin_bit_cast(unsigned, f);
    u = (u + 0x7FFFu + ((u >> 16) & 1u)) >> 16;   // RNE
    return (unsigned short)u;
}
__device__ __forceinline__ float bf2f(unsigned short s){
    unsigned u = ((unsigned)s) << 16;
    return __builtin_bit_cast(float, u);
}
// 5-inst tanh: exp saturates correctly at +/-inf, rcp ~1ulp (invisible at bf16)
__device__ __forceinline__ float tanh_cheap(float x){
    float e = __expf(2.f * x);
    float r = __builtin_amdgcn_rcpf(e + 1.f);
    return fmaf(-2.f, r, 1.f);
}
// legacy (fallback kernel only)
__device__ __forceinline__ float tanh_fast(float x){
    x = fminf(fmaxf(x, -12.f), 12.f);
    float e = __expf(2.f * x);
    return 1.f - 2.f / (e + 1.f);
}
// pack 2 f32 -> 2 bf16 (RNE), single instruction
__device__ __forceinline__ unsigned cvt_pk_bf16(float lo, float hi){
    unsigned r;
    asm("v_cvt_pk_bf16_f32 %0, %1, %2" : "=v"(r) : "v"(lo), "v"(hi));
    return r;
}
// swizzled short-index for a [row][128] bf16 LDS array (256B rows, 16B granule XOR)
__device__ __forceinline__ int swz(int row, int k){
    return row * 128 + ((((k >> 3) ^ (row & 15)) << 3) | (k & 7));
}

// ================= prep: posW1 (f32), W1 fragments, Wout^T ==========================
// W1FRAG layout: entry E = (A*4+ks)*64 + lane  (A = a-tile 0..7), 16B each.
__global__ __launch_bounds__(256) void sap_prep(
    const float* __restrict__ pos, const float* __restrict__ W1,
    const float* __restrict__ Wout, void* __restrict__ ws)
{
    const int t = threadIdx.x, blk = blockIdx.x;
    if (blk < 104){                       // posW1[l][a]; pad rows 0
        float* posW1 = (float*)((char*)ws + WS_POSW1);
        int l = blk * 2 + (t >> 7), a = t & 127;
        float acc = 0.f;
        if (l < Ln){
            #pragma unroll 4
            for (int k = 0; k < 128; ++k)
                acc += pos[l * En + k] * W1[k * An + a];
        }
        posW1[l * An + a] = acc;
    } else if (blk < 106){                // W1 fragments
        unsigned short* w1f = (unsigned short*)((char*)ws + WS_W1FRAG);
        int s = (blk - 104) * 256 + t;    // 0..511
        int lane = s & 63;
        int A = s >> 6;
        int c = lane & 15, q = lane >> 4;
        #pragma unroll
        for (int ks = 0; ks < 4; ++ks){
            unsigned short v[8];
            #pragma unroll
            for (int j = 0; j < 8; ++j)
                v[j] = f2bf(W1[(ks * 32 + q * 8 + j) * An + A * 16 + c]);
            *(bf16x8*)&w1f[(s * 4 + ks) * 8] = *(bf16x8*)v;
        }
    } else {                              // WoutT[e][k] bf16
        unsigned short* wt = (unsigned short*)((char*)ws + WS_WOUTT);
        int flat = ((blk - 106) * 256 + t) * 4;   // e*512+k
        int e = flat >> 9, k = flat & 511;
        unsigned short v[4];
        #pragma unroll
        for (int i = 0; i < 4; ++i)
            v[i] = f2bf(Wout[(size_t)(k + i) * En + e]);
        *(uint2*)&wt[flat] = *(uint2*)v;
    }
}

// ================= MAIN: fused att + online softmax + pooling =======================
// 1024 blocks (one per b) x 512 thr. 4 chunks of 64 l-rows, double-buffered staging.
// Wave w owns a-tile w in the MFMA phase; wave h (t<256) owns head h in the
// softmax phase; thread t owns pooled output (h=t>>7, e=t&127).
__global__ __launch_bounds__(512, 6) void sap_main3(
    const float* __restrict__ inp, const void* __restrict__ maskp,
    const float* __restrict__ W2, void* __restrict__ ws)
{
    __shared__ unsigned short s_x[2][64 * 128]; // 32 KB double-buffered bf16 x
    __shared__ float s_part[8][4][64];          // 8 KB per-wave partial att
    __shared__ float s_w[4][64];                // softmax weights (this chunk)
    __shared__ float s_scale[4];                // per-head rescale (this chunk)
    __shared__ float s_zfin[4];                 // final denominators

    const int t = threadIdx.x, lane = t & 63, w = t >> 6;
    const int c = lane & 15, q = lane >> 4;
    const int b = blockIdx.x;
    const int hh = t >> 7, ee = t & 127;        // pooled ownership

    const unsigned short* w1f   = (const unsigned short*)((char*)ws + WS_W1FRAG);
    const float*          posW1 = (const float*)((char*)ws + WS_POSW1);
    unsigned short*       slot  = (unsigned short*)((char*)ws + WS_ATTPOOL + (size_t)b * SLOT);

    // A-fragments + W2 rows (L2-hot)
    bf16x8 af[4];
    #pragma unroll
    for (int ks = 0; ks < 4; ++ks)
        af[ks] = *(const bf16x8*)&w1f[((w * 64 + lane) * 4 + ks) * 8];
    float4 w2a[4];
    #pragma unroll
    for (int v = 0; v < 4; ++v)
        w2a[v] = *(const float4*)&W2[(w * 16 + q * 4 + v) * Hn];

    // mask dtype detect (per-wave, no barrier)
    int flag;
    {
        unsigned word = ((const unsigned*)maskp)[lane];
        unsigned long long bi = __ballot(word > 1u);
        unsigned long long bfm = __ballot(word != 0u && word != 0x3F800000u);
        flag = (bi == 0ull) ? 0 : ((bfm == 0ull) ? 2 : 1);
    }

    const float4* in4 = (const float4*)(inp + (size_t)b * (Ln * En));

    // ---- prologue: stage chunk 0 into buffer 0 ----
    {
        float4 u0 = in4[t], u1 = in4[t + 512], u2 = in4[t + 1024], u3 = in4[t + 1536];
        #define PUTV(buf, vi, idx) { int ll = (idx) >> 5, kk = ((idx) & 31) * 4;             \
            uint2 val = make_uint2(cvt_pk_bf16(vi.x, vi.y), cvt_pk_bf16(vi.z, vi.w));        \
            *(uint2*)&s_x[buf][swz(ll, kk)] = val; }
        PUTV(0, u0, t) PUTV(0, u1, t + 512) PUTV(0, u2, t + 1024) PUTV(0, u3, t + 1536)
    }
    __syncthreads();

    float accp = 0.f;                     // pooled accumulator for (hh, ee)
    float Mh = -3.0e38f, Zh = 0.f;        // online softmax state (t<256 role)

    for (int cch = 0; cch < 4; ++cch){
        const int cur = cch & 1;
        const int NT = (cch < 3) ? 4 : 1;

        // ---- MFMA on buffer cur -> s_part ----
        for (int lt = 0; lt < NT; ++lt){
            int brow = lt * 16 + c;
            bf16x8 bfr[4];
            #pragma unroll
            for (int ks = 0; ks < 4; ++ks){
                int g = (ks * 4 + q) ^ c;
                bfr[ks] = *(bf16x8*)&s_x[cur][brow * 128 + (g << 3)];
            }
            f32x4 acc = *(const f32x4*)&posW1[(size_t)(cch * 64 + lt * 16 + c) * An + w * 16 + q * 4];
            #pragma unroll
            for (int ks = 0; ks < 4; ++ks)
                acc = __builtin_amdgcn_mfma_f32_16x16x32_bf16(af[ks], bfr[ks], acc, 0, 0, 0);
            float contrib[4] = {0.f, 0.f, 0.f, 0.f};
            #pragma unroll
            for (int v = 0; v < 4; ++v){
                float hv = tanh_cheap(acc[v]);
                contrib[0] += hv * w2a[v].x;
                contrib[1] += hv * w2a[v].y;
                contrib[2] += hv * w2a[v].z;
                contrib[3] += hv * w2a[v].w;
            }
            #pragma unroll
            for (int h = 0; h < 4; ++h){
                contrib[h] += __shfl_xor(contrib[h], 16, 64);
                contrib[h] += __shfl_xor(contrib[h], 32, 64);
            }
            s_part[w][q][lt * 16 + c] = contrib[q];
        }
        __syncthreads();

        // ---- issue next-chunk loads (consumed after the pool phase) ----
        float4 u0, u1, u2, u3;
        if (cch < 3){
            const int base = (cch + 1) * 2048;
            const float4 z4 = make_float4(0.f, 0.f, 0.f, 0.f);
            u0 = (base + t        < 6400) ? in4[base + t]        : z4;
            u1 = (base + t + 512  < 6400) ? in4[base + t + 512]  : z4;
            u2 = (base + t + 1024 < 6400) ? in4[base + t + 1024] : z4;
            u3 = (base + t + 1536 < 6400) ? in4[base + t + 1536] : z4;
        }

        // ---- online softmax update (t<256: wave h, lane l) ----
        if (t < 256){
            const int h = t >> 6, l = t & 63;
            float att = 0.f;
            #pragma unroll
            for (int w2 = 0; w2 < 8; ++w2) att += s_part[w2][h][l];
            int gl = cch * 64 + l;
            int mv = 0;
            if (gl < Ln){
                if (flag == 0)      mv = ((const int*)maskp)[b * Ln + gl] != 0;
                else if (flag == 1) mv = ((const unsigned char*)maskp)[b * Ln + gl] != 0;
                else                mv = ((const float*)maskp)[b * Ln + gl] != 0.f;
            }
            att = mv ? att : -1.0e30f;
            float cm = att;
            #pragma unroll
            for (int s = 32; s; s >>= 1) cm = fmaxf(cm, __shfl_xor(cm, s, 64));
            float Mn = fmaxf(Mh, cm);
            float sc = __expf(Mh - Mn);
            float wl = __expf(att - Mn);
            float zc = wl;
            #pragma unroll
            for (int s = 32; s; s >>= 1) zc += __shfl_xor(zc, s, 64);
            Zh = Zh * sc + zc;
            Mh = Mn;
            s_w[h][l] = wl;
            if (l == 0){
                s_scale[h] = sc;
                if (cch == 3) s_zfin[h] = Zh;
            }
        }
        __syncthreads();

        // ---- pool update: acc = acc*scale + sum_l w[l]*x[l][ee] ----
        {
            float a = accp * s_scale[hh];
            #pragma unroll 8
            for (int l = 0; l < 64; ++l)
                a = fmaf(s_w[hh][l], bf2f(s_x[cur][swz(l, ee)]), a);
            accp = a;
        }

        // ---- store staged next chunk into the other buffer ----
        if (cch < 3){
            const int base = (cch + 1) * 2048, nxt = cur ^ 1;
            (void)base;
            PUTV(nxt, u0, t) PUTV(nxt, u1, t + 512) PUTV(nxt, u2, t + 1024) PUTV(nxt, u3, t + 1536)
        }
        __syncthreads();
    }
    #undef PUTV

    // ---- write pooled bf16 (flat index h*128+e, matching WoutT k-order) ----
    slot[hh * En + ee] = f2bf(accp * (1.f / s_zfin[hh]));
}

// ================= K3: out = pooled @ Wout (MFMA) ===================================
__global__ __launch_bounds__(256) void sap_out(
    const void* __restrict__ ws, float* __restrict__ out)
{
    const unsigned short* wt = (const unsigned short*)((const char*)ws + WS_WOUTT);
    const int t = threadIdx.x, lane = t & 63, w = t >> 6;
    const int c = lane & 15, q = lane >> 4;
    const int b0 = blockIdx.x * 16;
    const int e0 = (blockIdx.y * 4 + w) * 16;

    const unsigned short* pslot =
        (const unsigned short*)((const char*)ws + WS_ATTPOOL + (size_t)(b0 + c) * SLOT);

    f32x4 acc = {0.f, 0.f, 0.f, 0.f};
    #pragma unroll 4
    for (int ks = 0; ks < 16; ++ks){
        bf16x8 afr = *(const bf16x8*)&pslot[ks * 32 + q * 8];
        bf16x8 bfr = *(const bf16x8*)&wt[(e0 + c) * 512 + ks * 32 + q * 8];
        acc = __builtin_amdgcn_mfma_f32_16x16x32_bf16(afr, bfr, acc, 0, 0, 0);
    }
    #pragma unroll
    for (int v = 0; v < 4; ++v)
        out[(size_t)(b0 + q * 4 + v) * En + e0 + c] = acc[v];
}

// ================= fallback (round-2 monolith) if ws ever shrinks ===================
__global__ __launch_bounds__(512, 4) void sap_fused_v2(
    const float* __restrict__ inp, const void* __restrict__ maskp,
    const float* __restrict__ pos, const float* __restrict__ W1,
    const float* __restrict__ W2, const float* __restrict__ Wout,
    float* __restrict__ out)
{
#define LP 208
    __shared__ unsigned short s_xp [LP * 128];
    __shared__ float s_att [4 * LP];
    __shared__ float s_mask[LP];
    __shared__ float s_pool[512];
    __shared__ float s_red [512];
    __shared__ int   s_flag;

    const int t = threadIdx.x;
    const int b = blockIdx.x;
    const int lane = t & 63, w = t >> 6;
    const int c = lane & 15, q = lane >> 4;

    if (t == 0){
        const unsigned* mw = (const unsigned*)maskp;
        int fi = 1, ff = 1;
        for (int i = 0; i < 64; ++i){
            unsigned word = mw[i];
            if (word > 1u) fi = 0;
            if (word != 0u && word != 0x3F800000u) ff = 0;
        }
        s_flag = fi ? 0 : (ff ? 2 : 1);
    }
    bf16x8 af[4];
    {
        const int arow = w * 16 + c;
        #pragma unroll
        for (int ks = 0; ks < 4; ++ks)
            #pragma unroll
            for (int j = 0; j < 8; ++j)
                af[ks][j] = (short)f2bf(W1[(ks * 32 + q * 8 + j) * An + arow]);
    }
    float w2a[4][4];
    #pragma unroll
    for (int v = 0; v < 4; ++v){
        float4 wv = *(const float4*)&W2[(w * 16 + q * 4 + v) * Hn];
        w2a[v][0] = wv.x; w2a[v][1] = wv.y; w2a[v][2] = wv.z; w2a[v][3] = wv.w;
    }
    __syncthreads();
    const int flag = s_flag;
    for (int l = t; l < LP; l += 512){
        float m = 0.f;
        if (l < Ln){
            int mv;
            if (flag == 0)      mv = ((const int*)maskp)[b * Ln + l] != 0;
            else if (flag == 1) mv = ((const unsigned char*)maskp)[b * Ln + l] != 0;
            else                mv = ((const float*)maskp)[b * Ln + l] != 0.f;
            m = mv ? 1.f : 0.f;
        }
        s_mask[l] = m;
    }
    for (int i = t; i < 4 * LP; i += 512) s_att[i] = 0.f;
    __syncthreads();
    {
        const float4* in4 = (const float4*)(inp + (size_t)b * (Ln * En));
        const float4* p4  = (const float4*)pos;
        #pragma unroll
        for (int it = 0; it < 13; ++it){
            int idx = it * 512 + t;
            int l = idx >> 5;
            int k = (idx & 31) * 4;
            uint2 val;
            if (idx < 6400){
                float m = s_mask[l];
                float4 a = in4[idx];
                float4 p = p4[idx];
                val = make_uint2((unsigned)f2bf(a.x*m+p.x) | ((unsigned)f2bf(a.y*m+p.y) << 16),
                                 (unsigned)f2bf(a.z*m+p.z) | ((unsigned)f2bf(a.w*m+p.w) << 16));
            } else val = make_uint2(0u, 0u);
            *(uint2*)&s_xp[swz(l, k)] = val;
        }
    }
    __syncthreads();
    for (int lt = 0; lt < 13; ++lt){
        int brow = lt * 16 + c;
        bf16x8 bfr[4];
        #pragma unroll
        for (int ks = 0; ks < 4; ++ks){
            int g = (ks * 4 + q) ^ c;
            bfr[ks] = *(bf16x8*)&s_xp[brow * 128 + (g << 3)];
        }
        f32x4 acc = {0.f, 0.f, 0.f, 0.f};
        #pragma unroll
        for (int ks = 0; ks < 4; ++ks)
            acc = __builtin_amdgcn_mfma_f32_16x16x32_bf16(af[ks], bfr[ks], acc, 0, 0, 0);
        float hv[4];
        #pragma unroll
        for (int v = 0; v < 4; ++v) hv[v] = tanh_fast(acc[v]);
        #pragma unroll
        for (int h = 0; h < 4; ++h){
            float contrib = hv[0]*w2a[0][h] + hv[1]*w2a[1][h] + hv[2]*w2a[2][h] + hv[3]*w2a[3][h];
            contrib += __shfl_xor(contrib, 16, 64);
            contrib += __shfl_xor(contrib, 32, 64);
            if (lane < 16) atomicAdd(&s_att[h * LP + lt * 16 + lane], contrib);
        }
    }
    __syncthreads();
    if (t < 256){
        const int sl = t & 63, h = t >> 6;
        float v[4]; bool ok[4]; float mx = -FLT_MAX;
        #pragma unroll
        for (int i = 0; i < 4; ++i){
            int l = sl + i * 64;
            ok[i] = (l < Ln) && (s_mask[l] > 0.5f);
            v[i]  = ok[i] ? s_att[h * LP + l] : -FLT_MAX;
            mx = fmaxf(mx, v[i]);
        }
        for (int s = 32; s; s >>= 1) mx = fmaxf(mx, __shfl_xor(mx, s, 64));
        float e[4]; float sum = 0.f;
        #pragma unroll
        for (int i = 0; i < 4; ++i){ e[i] = ok[i] ? __expf(v[i]-mx) : 0.f; sum += e[i]; }
        for (int s = 32; s; s >>= 1) sum += __shfl_xor(sum, s, 64);
        float inv = 1.f / sum;
        #pragma unroll
        for (int i = 0; i < 4; ++i){ int l = sl + i*64; if (l < LP) s_att[h*LP+l] = e[i]*inv; }
    }
    __syncthreads();
    {
        int h = t >> 7, e = t & 127;
        float acc = 0.f;
        #pragma unroll 4
        for (int l = 0; l < Ln; ++l){
            float xv = bf2f(s_xp[swz(l, e)]) - pos[l * En + e];
            acc += s_att[h * LP + l] * xv;
        }
        s_pool[h * En + e] = acc;
    }
    __syncthreads();
    {
        int qt = t >> 7, e = t & 127;
        float acc = 0.f;
        const float* wo = Wout + (size_t)(qt * 128) * En + e;
        #pragma unroll 4
        for (int i = 0; i < 128; ++i)
            acc += s_pool[qt * 128 + i] * wo[(size_t)i * En];
        s_red[t] = acc;
    }
    __syncthreads();
    if (t < 128)
        out[(size_t)b * En + t] = s_red[t] + s_red[t + 128] + s_red[t + 256] + s_red[t + 384];
#undef LP
}

extern "C" void kernel_launch(void* const* d_in, const int* in_sizes, int n_in,
                              void* d_out, int out_size, void* d_ws, size_t ws_size,
                              hipStream_t stream)
{
    const float* inp  = (const float*)d_in[0];
    const void*  mask = d_in[1];
    const float* pos  = (const float*)d_in[2];
    const float* W1   = (const float*)d_in[3];
    const float* W2   = (const float*)d_in[4];
    const float* Wout = (const float*)d_in[5];
    float* out = (float*)d_out;

    if (ws_size >= WS_NEEDED){
        sap_prep<<<170, 256, 0, stream>>>(pos, W1, Wout, d_ws);
        sap_main3<<<Bn, 512, 0, stream>>>(inp, mask, W2, d_ws);
        sap_out<<<dim3(64, 2), 256, 0, stream>>>(d_ws, out);
    } else {
        sap_fused_v2<<<Bn, 512, 0, stream>>>(inp, mask, pos, W1, W2, Wout, out);
    }
}

// Round 10
// 77.186 us; speedup vs baseline: 1.2356x; 1.2356x over previous
//
#include <hip/hip_runtime.h>
#include <cfloat>

#define Bn 1024
#define Ln 200
#define En 128
#define An 128
#define Hn 4

// ---- ws layout (total 1974272 B; proven ws_size >= 2363392) ----
#define WS_POSW1   0                        // 208*128*4 = 106496 (rows 200..207 zero)
#define WS_W1FRAG  106496                   // 2048 entries * 16B = 32768
#define WS_ATTPOOL 139264                   // 1024 slots * SLOT (pooled bf16[512] per b)
#define SLOT       1664
#define WS_WOUTT   1843200                  // 128*512 bf16 = 131072
#define WS_NEEDED  1974272

using f32x4  = __attribute__((ext_vector_type(4))) float;
using bf16x8 = __attribute__((ext_vector_type(8))) short;

__device__ __forceinline__ unsigned short f2bf(float f){
    unsigned u = __builtin_bit_cast(unsigned, f);
    u = (u + 0x7FFFu + ((u >> 16) & 1u)) >> 16;   // RNE
    return (unsigned short)u;
}
__device__ __forceinline__ float bf2f(unsigned short s){
    unsigned u = ((unsigned)s) << 16;
    return __builtin_bit_cast(float, u);
}
// 5-inst tanh
__device__ __forceinline__ float tanh_cheap(float x){
    float e = __expf(2.f * x);
    float r = __builtin_amdgcn_rcpf(e + 1.f);
    return fmaf(-2.f, r, 1.f);
}
// legacy (fallback kernel only)
__device__ __forceinline__ float tanh_fast(float x){
    x = fminf(fmaxf(x, -12.f), 12.f);
    float e = __expf(2.f * x);
    return 1.f - 2.f / (e + 1.f);
}
// pack 2 f32 -> 2 bf16 (RNE), single instruction
__device__ __forceinline__ unsigned cvt_pk_bf16(float lo, float hi){
    unsigned r;
    asm("v_cvt_pk_bf16_f32 %0, %1, %2" : "=v"(r) : "v"(lo), "v"(hi));
    return r;
}
// swizzled short-index for a [row][128] bf16 LDS array (fallback kernel only)
__device__ __forceinline__ int swz(int row, int k){
    return row * 128 + ((((k >> 3) ^ (row & 15)) << 3) | (k & 7));
}

// ================= prep: posW1 (f32), W1 fragments, Wout^T ==========================
// W1FRAG layout: entry E = (A*4+ks)*64 + lane  (A = a-tile 0..7), 16B each.
__global__ __launch_bounds__(256) void sap_prep(
    const float* __restrict__ pos, const float* __restrict__ W1,
    const float* __restrict__ Wout, void* __restrict__ ws)
{
    const int t = threadIdx.x, blk = blockIdx.x;
    if (blk < 104){                       // posW1[l][a]; pad rows 0
        float* posW1 = (float*)((char*)ws + WS_POSW1);
        int l = blk * 2 + (t >> 7), a = t & 127;
        float acc = 0.f;
        if (l < Ln){
            #pragma unroll 4
            for (int k = 0; k < 128; ++k)
                acc += pos[l * En + k] * W1[k * An + a];
        }
        posW1[l * An + a] = acc;
    } else if (blk < 106){                // W1 fragments
        unsigned short* w1f = (unsigned short*)((char*)ws + WS_W1FRAG);
        int s = (blk - 104) * 256 + t;    // 0..511
        int lane = s & 63;
        int A = s >> 6;
        int c = lane & 15, q = lane >> 4;
        #pragma unroll
        for (int ks = 0; ks < 4; ++ks){
            unsigned short v[8];
            #pragma unroll
            for (int j = 0; j < 8; ++j)
                v[j] = f2bf(W1[(ks * 32 + q * 8 + j) * An + A * 16 + c]);
            *(bf16x8*)&w1f[(s * 4 + ks) * 8] = *(bf16x8*)v;
        }
    } else {                              // WoutT[e][k] bf16
        unsigned short* wt = (unsigned short*)((char*)ws + WS_WOUTT);
        int flat = ((blk - 106) * 256 + t) * 4;   // e*512+k
        int e = flat >> 9, k = flat & 511;
        unsigned short v[4];
        #pragma unroll
        for (int i = 0; i < 4; ++i)
            v[i] = f2bf(Wout[(size_t)(k + i) * En + e]);
        *(uint2*)&wt[flat] = *(uint2*)v;
    }
}

// ================= MAIN: fused att + online softmax + pooling (f32 LDS) =============
// 1024 blocks x 512 thr. 4 chunks of 64 l-rows, SINGLE f32 buffer, granule-XOR swizzle.
// Staging is straight-line (no register liveness across barriers -> no spill).
__global__ __launch_bounds__(512, 4) void sap_main5(
    const float* __restrict__ inp, const void* __restrict__ maskp,
    const float* __restrict__ W2, void* __restrict__ ws)
{
    __shared__ float s_xf[64 * 128];            // 32 KB f32 x-chunk, granule-swizzled
    __shared__ float s_part[8][4][64];          // 8 KB per-wave partial att
    __shared__ float s_w[4][64];                // softmax weights (this chunk)
    __shared__ float s_scale[4];                // per-head rescale
    __shared__ float s_zfin[4];                 // final denominators
    __shared__ float s_mask[256];               // mask (pad rows 0)

    const int t = threadIdx.x, lane = t & 63, w = t >> 6;
    const int c = lane & 15, q = lane >> 4;
    const int b = blockIdx.x;
    const int hh = t >> 7, ee = t & 127;        // pooled ownership

    const unsigned short* w1f   = (const unsigned short*)((char*)ws + WS_W1FRAG);
    const float*          posW1 = (const float*)((char*)ws + WS_POSW1);
    unsigned short*       slot  = (unsigned short*)((char*)ws + WS_ATTPOOL + (size_t)b * SLOT);

    // A-fragments + W2 rows (L2-hot)
    bf16x8 af[4];
    #pragma unroll
    for (int ks = 0; ks < 4; ++ks)
        af[ks] = *(const bf16x8*)&w1f[((w * 64 + lane) * 4 + ks) * 8];
    float4 w2a[4];
    #pragma unroll
    for (int v = 0; v < 4; ++v)
        w2a[v] = *(const float4*)&W2[(w * 16 + q * 4 + v) * Hn];

    // prologue: mask dtype detect (per-wave) + stage full mask to LDS
    {
        unsigned word = ((const unsigned*)maskp)[lane];
        unsigned long long bi  = __ballot(word > 1u);
        unsigned long long bfm = __ballot(word != 0u && word != 0x3F800000u);
        int flag = (bi == 0ull) ? 0 : ((bfm == 0ull) ? 2 : 1);
        if (t < 256){
            float m = 0.f;
            if (t < Ln){
                int mv;
                if (flag == 0)      mv = ((const int*)maskp)[b * Ln + t] != 0;
                else if (flag == 1) mv = ((const unsigned char*)maskp)[b * Ln + t] != 0;
                else                mv = ((const float*)maskp)[b * Ln + t] != 0.f;
                m = mv ? 1.f : 0.f;
            }
            s_mask[t] = m;
        }
    }
    __syncthreads();

    const float4* in4 = (const float4*)(inp + (size_t)b * (Ln * En));
    float accp = 0.f;                     // pooled accumulator for (hh, ee)
    float Mh = -3.0e38f, Zh = 0.f;        // online softmax state (t<256 role)

    for (int cch = 0; cch < 4; ++cch){
        const int NT = (cch < 3) ? 4 : 1;
        const int base4 = cch * 2048;

        // ---- stage chunk (straight-line; f32, granule-XOR swizzle) ----
        {
            const float4 z4 = make_float4(0.f, 0.f, 0.f, 0.f);
            float4 u0, u1, u2, u3;
            if (cch < 3){
                u0 = in4[base4 + t];        u1 = in4[base4 + t + 512];
                u2 = in4[base4 + t + 1024]; u3 = in4[base4 + t + 1536];
            } else {
                u0 = (t < 256) ? in4[base4 + t] : z4;
                u1 = z4; u2 = z4; u3 = z4;
            }
            #define PUTG(vi, i) { int row = (i) >> 5, g = (i) & 31;                     \
                *(f32x4*)&s_xf[row * 128 + ((g ^ (row & 7)) << 2)] =                    \
                    *(const f32x4*)&vi; }
            PUTG(u0, t) PUTG(u1, t + 512) PUTG(u2, t + 1024) PUTG(u3, t + 1536)
            #undef PUTG
        }
        __syncthreads();

        // ---- MFMA (C-init = posW1) -> tanh -> dot W2 -> wave reduce -> s_part ----
        for (int lt = 0; lt < NT; ++lt){
            const int brow = lt * 16 + c;
            const int xr = brow & 7;
            const f32x4* xg = (const f32x4*)&s_xf[brow * 128];
            bf16x8 bfr[4];
            #pragma unroll
            for (int ks = 0; ks < 4; ++ks){
                int g0 = ks * 8 + q * 2;
                f32x4 a4 = xg[(g0    ) ^ xr];
                f32x4 b4 = xg[(g0 + 1) ^ xr];
                unsigned r0 = cvt_pk_bf16(a4[0], a4[1]);
                unsigned r1 = cvt_pk_bf16(a4[2], a4[3]);
                unsigned r2 = cvt_pk_bf16(b4[0], b4[1]);
                unsigned r3 = cvt_pk_bf16(b4[2], b4[3]);
                uint4 packed = make_uint4(r0, r1, r2, r3);
                bfr[ks] = __builtin_bit_cast(bf16x8, packed);
            }
            f32x4 acc = *(const f32x4*)&posW1[(size_t)(cch * 64 + brow) * An + w * 16 + q * 4];
            #pragma unroll
            for (int ks = 0; ks < 4; ++ks)
                acc = __builtin_amdgcn_mfma_f32_16x16x32_bf16(af[ks], bfr[ks], acc, 0, 0, 0);
            float contrib[4] = {0.f, 0.f, 0.f, 0.f};
            #pragma unroll
            for (int v = 0; v < 4; ++v){
                float hv = tanh_cheap(acc[v]);
                contrib[0] += hv * w2a[v].x;
                contrib[1] += hv * w2a[v].y;
                contrib[2] += hv * w2a[v].z;
                contrib[3] += hv * w2a[v].w;
            }
            #pragma unroll
            for (int h = 0; h < 4; ++h){
                contrib[h] += __shfl_xor(contrib[h], 16, 64);
                contrib[h] += __shfl_xor(contrib[h], 32, 64);
            }
            s_part[w][q][lt * 16 + c] = contrib[q];
        }
        __syncthreads();

        // ---- online softmax update (t<256: wave h, lane l) ----
        if (t < 256){
            const int h = t >> 6, l = t & 63;
            float att = 0.f;
            #pragma unroll
            for (int w2 = 0; w2 < 8; ++w2) att += s_part[w2][h][l];
            float mvf = s_mask[cch * 64 + l];
            att = (mvf > 0.5f) ? att : -1.0e30f;
            float cm = att;
            #pragma unroll
            for (int s = 32; s; s >>= 1) cm = fmaxf(cm, __shfl_xor(cm, s, 64));
            float Mn = fmaxf(Mh, cm);
            float sc = __expf(Mh - Mn);
            float wl = __expf(att - Mn);
            float zc = wl;
            #pragma unroll
            for (int s = 32; s; s >>= 1) zc += __shfl_xor(zc, s, 64);
            Zh = Zh * sc + zc;
            Mh = Mn;
            s_w[h][l] = wl;
            if (l == 0){
                s_scale[h] = sc;
                if (cch == 3) s_zfin[h] = Zh;
            }
        }
        __syncthreads();

        // ---- pool update: acc = acc*scale + sum_l w[l]*x_f32[l][ee] ----
        {
            const int eg = ee >> 2, eo = ee & 3;
            float a = accp * s_scale[hh];
            #pragma unroll 8
            for (int l = 0; l < 64; ++l)
                a = fmaf(s_w[hh][l], s_xf[l * 128 + ((eg ^ (l & 7)) << 2) + eo], a);
            accp = a;
        }
        __syncthreads();
    }

    // ---- write pooled bf16 (flat index h*128+e, matching WoutT k-order) ----
    slot[hh * En + ee] = f2bf(accp * __builtin_amdgcn_rcpf(s_zfin[hh]));
}

// ================= K3: out = pooled @ Wout (MFMA) ===================================
__global__ __launch_bounds__(256) void sap_out(
    const void* __restrict__ ws, float* __restrict__ out)
{
    const unsigned short* wt = (const unsigned short*)((const char*)ws + WS_WOUTT);
    const int t = threadIdx.x, lane = t & 63, w = t >> 6;
    const int c = lane & 15, q = lane >> 4;
    const int b0 = blockIdx.x * 16;
    const int e0 = (blockIdx.y * 4 + w) * 16;

    const unsigned short* pslot =
        (const unsigned short*)((const char*)ws + WS_ATTPOOL + (size_t)(b0 + c) * SLOT);

    f32x4 acc = {0.f, 0.f, 0.f, 0.f};
    #pragma unroll 4
    for (int ks = 0; ks < 16; ++ks){
        bf16x8 afr = *(const bf16x8*)&pslot[ks * 32 + q * 8];
        bf16x8 bfr = *(const bf16x8*)&wt[(e0 + c) * 512 + ks * 32 + q * 8];
        acc = __builtin_amdgcn_mfma_f32_16x16x32_bf16(afr, bfr, acc, 0, 0, 0);
    }
    #pragma unroll
    for (int v = 0; v < 4; ++v)
        out[(size_t)(b0 + q * 4 + v) * En + e0 + c] = acc[v];
}

// ================= fallback (round-2 monolith) if ws ever shrinks ===================
__global__ __launch_bounds__(512, 4) void sap_fused_v2(
    const float* __restrict__ inp, const void* __restrict__ maskp,
    const float* __restrict__ pos, const float* __restrict__ W1,
    const float* __restrict__ W2, const float* __restrict__ Wout,
    float* __restrict__ out)
{
#define LP 208
    __shared__ unsigned short s_xp [LP * 128];
    __shared__ float s_att [4 * LP];
    __shared__ float s_mask[LP];
    __shared__ float s_pool[512];
    __shared__ float s_red [512];
    __shared__ int   s_flag;

    const int t = threadIdx.x;
    const int b = blockIdx.x;
    const int lane = t & 63, w = t >> 6;
    const int c = lane & 15, q = lane >> 4;

    if (t == 0){
        const unsigned* mw = (const unsigned*)maskp;
        int fi = 1, ff = 1;
        for (int i = 0; i < 64; ++i){
            unsigned word = mw[i];
            if (word > 1u) fi = 0;
            if (word != 0u && word != 0x3F800000u) ff = 0;
        }
        s_flag = fi ? 0 : (ff ? 2 : 1);
    }
    bf16x8 af[4];
    {
        const int arow = w * 16 + c;
        #pragma unroll
        for (int ks = 0; ks < 4; ++ks)
            #pragma unroll
            for (int j = 0; j < 8; ++j)
                af[ks][j] = (short)f2bf(W1[(ks * 32 + q * 8 + j) * An + arow]);
    }
    float w2a[4][4];
    #pragma unroll
    for (int v = 0; v < 4; ++v){
        float4 wv = *(const float4*)&W2[(w * 16 + q * 4 + v) * Hn];
        w2a[v][0] = wv.x; w2a[v][1] = wv.y; w2a[v][2] = wv.z; w2a[v][3] = wv.w;
    }
    __syncthreads();
    const int flag = s_flag;
    for (int l = t; l < LP; l += 512){
        float m = 0.f;
        if (l < Ln){
            int mv;
            if (flag == 0)      mv = ((const int*)maskp)[b * Ln + l] != 0;
            else if (flag == 1) mv = ((const unsigned char*)maskp)[b * Ln + l] != 0;
            else                mv = ((const float*)maskp)[b * Ln + l] != 0.f;
            m = mv ? 1.f : 0.f;
        }
        s_mask[l] = m;
    }
    for (int i = t; i < 4 * LP; i += 512) s_att[i] = 0.f;
    __syncthreads();
    {
        const float4* in4 = (const float4*)(inp + (size_t)b * (Ln * En));
        const float4* p4  = (const float4*)pos;
        #pragma unroll
        for (int it = 0; it < 13; ++it){
            int idx = it * 512 + t;
            int l = idx >> 5;
            int k = (idx & 31) * 4;
            uint2 val;
            if (idx < 6400){
                float m = s_mask[l];
                float4 a = in4[idx];
                float4 p = p4[idx];
                val = make_uint2((unsigned)f2bf(a.x*m+p.x) | ((unsigned)f2bf(a.y*m+p.y) << 16),
                                 (unsigned)f2bf(a.z*m+p.z) | ((unsigned)f2bf(a.w*m+p.w) << 16));
            } else val = make_uint2(0u, 0u);
            *(uint2*)&s_xp[swz(l, k)] = val;
        }
    }
    __syncthreads();
    for (int lt = 0; lt < 13; ++lt){
        int brow = lt * 16 + c;
        bf16x8 bfr[4];
        #pragma unroll
        for (int ks = 0; ks < 4; ++ks){
            int g = (ks * 4 + q) ^ c;
            bfr[ks] = *(bf16x8*)&s_xp[brow * 128 + (g << 3)];
        }
        f32x4 acc = {0.f, 0.f, 0.f, 0.f};
        #pragma unroll
        for (int ks = 0; ks < 4; ++ks)
            acc = __builtin_amdgcn_mfma_f32_16x16x32_bf16(af[ks], bfr[ks], acc, 0, 0, 0);
        float hv[4];
        #pragma unroll
        for (int v = 0; v < 4; ++v) hv[v] = tanh_fast(acc[v]);
        #pragma unroll
        for (int h = 0; h < 4; ++h){
            float contrib = hv[0]*w2a[0][h] + hv[1]*w2a[1][h] + hv[2]*w2a[2][h] + hv[3]*w2a[3][h];
            contrib += __shfl_xor(contrib, 16, 64);
            contrib += __shfl_xor(contrib, 32, 64);
            if (lane < 16) atomicAdd(&s_att[h * LP + lt * 16 + lane], contrib);
        }
    }
    __syncthreads();
    if (t < 256){
        const int sl = t & 63, h = t >> 6;
        float v[4]; bool ok[4]; float mx = -FLT_MAX;
        #pragma unroll
        for (int i = 0; i < 4; ++i){
            int l = sl + i * 64;
            ok[i] = (l < Ln) && (s_mask[l] > 0.5f);
            v[i]  = ok[i] ? s_att[h * LP + l] : -FLT_MAX;
            mx = fmaxf(mx, v[i]);
        }
        for (int s = 32; s; s >>= 1) mx = fmaxf(mx, __shfl_xor(mx, s, 64));
        float e[4]; float sum = 0.f;
        #pragma unroll
        for (int i = 0; i < 4; ++i){ e[i] = ok[i] ? __expf(v[i]-mx) : 0.f; sum += e[i]; }
        for (int s = 32; s; s >>= 1) sum += __shfl_xor(sum, s, 64);
        float inv = 1.f / sum;
        #pragma unroll
        for (int i = 0; i < 4; ++i){ int l = sl + i*64; if (l < LP) s_att[h*LP+l] = e[i]*inv; }
    }
    __syncthreads();
    {
        int h = t >> 7, e = t & 127;
        float acc = 0.f;
        #pragma unroll 4
        for (int l = 0; l < Ln; ++l){
            float xv = bf2f(s_xp[swz(l, e)]) - pos[l * En + e];
            acc += s_att[h * LP + l] * xv;
        }
        s_pool[h * En + e] = acc;
    }
    __syncthreads();
    {
        int qt = t >> 7, e = t & 127;
        float acc = 0.f;
        const float* wo = Wout + (size_t)(qt * 128) * En + e;
        #pragma unroll 4
        for (int i = 0; i < 128; ++i)
            acc += s_pool[qt * 128 + i] * wo[(size_t)i * En];
        s_red[t] = acc;
    }
    __syncthreads();
    if (t < 128)
        out[(size_t)b * En + t] = s_red[t] + s_red[t + 128] + s_red[t + 256] + s_red[t + 384];
#undef LP
}

extern "C" void kernel_launch(void* const* d_in, const int* in_sizes, int n_in,
                              void* d_out, int out_size, void* d_ws, size_t ws_size,
                              hipStream_t stream)
{
    const float* inp  = (const float*)d_in[0];
    const void*  mask = d_in[1];
    const float* pos  = (const float*)d_in[2];
    const float* W1   = (const float*)d_in[3];
    const float* W2   = (const float*)d_in[4];
    const float* Wout = (const float*)d_in[5];
    float* out = (float*)d_out;

    if (ws_size >= WS_NEEDED){
        sap_prep<<<170, 256, 0, stream>>>(pos, W1, Wout, d_ws);
        sap_main5<<<Bn, 512, 0, stream>>>(inp, mask, W2, d_ws);
        sap_out<<<dim3(64, 2), 256, 0, stream>>>(d_ws, out);
    } else {
        sap_fused_v2<<<Bn, 512, 0, stream>>>(inp, mask, pos, W1, W2, Wout, out);
    }
}